// Round 12
// baseline (181.393 us; speedup 1.0000x reference)
//
#include <hip/hip_runtime.h>
#include <hip/hip_bf16.h>
#include <math.h>

// Problem constants
#define BROWS 16384
#define IN_DIM 128
#define HID 512
#define ATT 256
#define KTOT 896          // IN_DIM + HID + ATT
#define KC_TOT 112        // KTOT / 8

typedef __bf16 bf16x8 __attribute__((ext_vector_type(8)));
typedef float f32x4 __attribute__((ext_vector_type(4)));

// ---------------------------------------------------------------------------
// Kernel 1: pack augmented weights -> B_stage[jt(8)][kc(112)][nl(192)][8] bf16.
// nl = jg*48 + type*16 + j16 ; jg in [0,4), type 0=gate 1=dyn 2=tau.
// j = jt*64 + jg*16 + j16. tau rows ZERO outside k in [128,640).   (UNCHANGED)
// ---------------------------------------------------------------------------
__device__ __forceinline__ float softplus_f(float x) {
    return fmaxf(x, 0.0f) + log1pf(__expf(-fabsf(x)));
}

__global__ void pack_B(const float* __restrict__ W_gd, const float* __restrict__ W_tau,
                       const float* __restrict__ gleak, const float* __restrict__ cm,
                       __hip_bfloat16* __restrict__ B_stage, float* __restrict__ dconst) {
    const int cid = blockIdx.x * 256 + threadIdx.x;   // 672*256 = 172032 = 8*112*192
    if (cid < HID) {
        dconst[cid] = softplus_f(cm[cid]) + softplus_f(gleak[cid]) + 1e-6f;
    }
    const int nl = cid % 192;
    const int kc = (cid / 192) % KC_TOT;
    const int jt = cid / (192 * KC_TOT);
    const int jg = nl / 48, type = (nl % 48) / 16, j16 = nl % 16;
    const int j = jt * 64 + jg * 16 + j16;
    const int k0 = kc * 8;

    float v[8];
    if (type == 0) {
        const float* s = W_gd + (size_t)j * KTOT + k0;
        #pragma unroll
        for (int i = 0; i < 8; ++i) v[i] = s[i];
    } else if (type == 1) {
        const float* s = W_gd + (size_t)(HID + j) * KTOT + k0;
        #pragma unroll
        for (int i = 0; i < 8; ++i) v[i] = s[i];
    } else {
        if (k0 >= IN_DIM && k0 < IN_DIM + HID) {
            const float* s = W_tau + (size_t)j * HID + (k0 - IN_DIM);
            #pragma unroll
            for (int i = 0; i < 8; ++i) v[i] = s[i];
        } else {
            #pragma unroll
            for (int i = 0; i < 8; ++i) v[i] = 0.0f;
        }
    }
    union { __hip_bfloat16 hh[8]; uint4 u; } p;
    #pragma unroll
    for (int i = 0; i < 8; ++i) p.hh[i] = __float2bfloat16(v[i]);
    *(uint4*)(B_stage + (size_t)cid * 8) = p.u;
}

// ---------------------------------------------------------------------------
// Kernel 2 — R12: m97-style windowed LDS pipeline for B (structural change).
// R11 falsified the L2-thrash theory (nt = -4us). Invariant across R0-R11
// (64-72us, MfmaUtil 20-23% over every occupancy/burst/traffic config) =>
// per-wave register pipelines cannot cover B's L2 latency at <=2 waves/SIMD
// (empirical VGPR law: >64 regs => 8 waves/CU max; compiler compresses all
// source rings to ~distance-1, m131-m141). Fix: serve B from LDS (~120cyc)
// staged in bulk via global_load_lds, double-buffered K=32 windows, ONE
// barrier per window (the proven 874-TF m97 schedule).
//   Block: 512 thr / 8 waves = 64 rows x 256 j. Wave = 64r x 32j,
//   acc[4rf][2jf][3ty] = 96 VGPR; per-jf MFMA passes keep peak ~118 < 128.
//   LDS/buf: B 48KB ([kcl4][jtl4][nl192][16B]) + A 4KB ([kcl4][row64][16B],
//   row^((kc)&31) swizzle = R2's proven conflict-free pattern). 2 bufs=104KB.
//   Grid 512 = 256 rowtiles x 2 jtiles; XCD-chunk swizzle co-locates a
//   rowtile's two jtiles on one XCD so the A fp32 re-read hits L2.
//   B L2 traffic 688MB; window ~= max(780cyc MFMA, ~800cyc B-stage) => core
//   ~22us + ingest/epilogue => predict 35-48us total.
// Fragment maps are verbatim from the PASSING R2 kernel (B chunk =
// B_stage[jt][kc=kw*4+q][jg*48+ty*16+t]; A row^(kc&31); C row=q*4+r, col=t).
// ---------------------------------------------------------------------------
#define LDSB 49152            // B region bytes per buffer
#define LDSBUF 53248          // B + A(4096) per buffer

__global__ __launch_bounds__(512, 2) void ltc_gemm(
    const float* __restrict__ x, const float* __restrict__ h_ltc,
    const float* __restrict__ ctx, const __hip_bfloat16* __restrict__ B_stage,
    const float* __restrict__ b_gd, const float* __restrict__ b_tau,
    const float* __restrict__ dconst, float* __restrict__ out) {

    __shared__ __attribute__((aligned(16))) char Lds[2][LDSBUF];

    // bijective XCD-chunk swizzle: 512 wgs = 8 xcds x (32 rowtiles x 2 jtiles)
    const int wgid = blockIdx.x;
    const int xcd = wgid & 7;
    const int k2 = wgid >> 3;            // 0..63
    const int jt2 = k2 & 1;              // j-tile 0/1 (256 j each)
    const int rt = xcd * 32 + (k2 >> 1); // row-tile 0..255 (64 rows each)
    const int jtBase = jt2 * 4;          // B_stage jt units 0..3 or 4..7

    const int tid = threadIdx.x;
    const int wave = tid >> 6, lane = tid & 63;
    const int q = lane >> 4, t = lane & 15;

    // ---- per-thread B gll source byte-offsets; advance 12288 B per window ----
    int bo[6];
    #pragma unroll
    for (int i = 0; i < 6; ++i) {
        const int n = i * 512 + tid;           // chunk id 0..3071
        const int kcl = n / 768;               // 0..3
        const int jtl = (n / 192) & 3;         // 0..3
        const int nl  = n - (n / 192) * 192;   // 0..191
        bo[i] = (((jtBase + jtl) * KC_TOT + kcl) * 192 + nl) * 16;
    }
    const char* bsrc = (const char*)B_stage;

    // ---- A stager roles (threads 0..255: row 0..63 x chunk 0..3) ----
    const int arow = (tid & 255) >> 2;
    const int ach  = tid & 3;

    // ---- prologue: stage window 0 into buf 0 ----
    #pragma unroll
    for (int i = 0; i < 6; ++i) {
        const int n = i * 512 + tid;
        __builtin_amdgcn_global_load_lds(
            (const __attribute__((address_space(1))) void*)(bsrc + bo[i]),
            (__attribute__((address_space(3))) void*)(&Lds[0][n * 16]), 16, 0, 0);
    }
    if (tid < 256) {
        const float* p = x + (size_t)(rt * 64 + arow) * IN_DIM + ach * 8;  // window 0 = x cols 0..31
        float4 v0 = *(const float4*)p;
        float4 v1 = *(const float4*)(p + 4);
        union { __hip_bfloat16 hh[8]; uint4 u; } pk;
        pk.hh[0]=__float2bfloat16(v0.x); pk.hh[1]=__float2bfloat16(v0.y);
        pk.hh[2]=__float2bfloat16(v0.z); pk.hh[3]=__float2bfloat16(v0.w);
        pk.hh[4]=__float2bfloat16(v1.x); pk.hh[5]=__float2bfloat16(v1.y);
        pk.hh[6]=__float2bfloat16(v1.z); pk.hh[7]=__float2bfloat16(v1.w);
        *(uint4*)(&Lds[0][LDSB + ((ach * 64 + (arow ^ (ach & 31))) << 4)]) = pk.u;
    }

    f32x4 acc[4][2][3];
    #pragma unroll
    for (int rf = 0; rf < 4; ++rf)
        #pragma unroll
        for (int jf = 0; jf < 2; ++jf)
            #pragma unroll
            for (int ty = 0; ty < 3; ++ty) acc[rf][jf][ty] = (f32x4)0.0f;

    // B-frag base byte offset within buffer for this lane:
    // ((q*4 + wave>>1)*192 + (wave&1)*96 + t)*16 ; + jf*768 + ty*256
    const int bOff = ((q * 4 + (wave >> 1)) * 192 + (wave & 1) * 96 + t) * 16;

    for (int kw = 0; kw < 28; ++kw) {
        const int cur = kw & 1, nxt = cur ^ 1;
        __syncthreads();   // drains prev window's staging (vmcnt/lgkmcnt) + readers

        float4 av0, av1;
        const int kwn = kw + 1;
        if (kw < 27) {
            // issue next B window into Lds[nxt] (async, drains at NEXT barrier)
            #pragma unroll
            for (int i = 0; i < 6; ++i) {
                bo[i] += 12288;                         // +4 kc * 192 * 16B
                const int n = i * 512 + tid;
                __builtin_amdgcn_global_load_lds(
                    (const __attribute__((address_space(1))) void*)(bsrc + bo[i]),
                    (__attribute__((address_space(3))) void*)(&Lds[nxt][n * 16]), 16, 0, 0);
            }
            // issue next A window loads into regs (HBM latency hides under MFMA)
            if (tid < 256) {
                const float* asrc; int ars, acol;
                if (kwn < 4)       { asrc = x;     ars = IN_DIM; acol = kwn * 32; }
                else if (kwn < 20) { asrc = h_ltc; ars = HID;    acol = kwn * 32 - 128; }
                else               { asrc = ctx;   ars = ATT;    acol = kwn * 32 - 640; }
                const float* p = asrc + (size_t)(rt * 64 + arow) * ars + acol + ach * 8;
                av0 = *(const float4*)p;
                av1 = *(const float4*)(p + 4);
            }
        }

        // ---- compute current window: 12-20 MFMA per wave ----
        const bool tau_cur = (kw >= 4 && kw < 20);   // k in [128,640)
        const char* Bc = Lds[cur];
        const char* Ac = Lds[cur] + LDSB;
        #pragma unroll
        for (int jf = 0; jf < 2; ++jf) {
            const bf16x8 bg = *(const bf16x8*)(Bc + bOff + jf * 768);
            const bf16x8 bd = *(const bf16x8*)(Bc + bOff + jf * 768 + 256);
            bf16x8 bt;
            if (tau_cur) bt = *(const bf16x8*)(Bc + bOff + jf * 768 + 512);
            #pragma unroll
            for (int rf = 0; rf < 4; ++rf) {
                const int row = rf * 16 + t;
                const bf16x8 a = *(const bf16x8*)(Ac + ((q * 64 + (row ^ ((kw * 4 + q) & 31))) << 4));
                acc[rf][jf][0] = __builtin_amdgcn_mfma_f32_16x16x32_bf16(a, bg, acc[rf][jf][0], 0, 0, 0);
                acc[rf][jf][1] = __builtin_amdgcn_mfma_f32_16x16x32_bf16(a, bd, acc[rf][jf][1], 0, 0, 0);
                if (tau_cur)
                    acc[rf][jf][2] = __builtin_amdgcn_mfma_f32_16x16x32_bf16(a, bt, acc[rf][jf][2], 0, 0, 0);
            }
        }

        // ---- finish A staging for next window (cvt + LDS write) ----
        if (kw < 27 && tid < 256) {
            union { __hip_bfloat16 hh[8]; uint4 u; } pk;
            pk.hh[0]=__float2bfloat16(av0.x); pk.hh[1]=__float2bfloat16(av0.y);
            pk.hh[2]=__float2bfloat16(av0.z); pk.hh[3]=__float2bfloat16(av0.w);
            pk.hh[4]=__float2bfloat16(av1.x); pk.hh[5]=__float2bfloat16(av1.y);
            pk.hh[6]=__float2bfloat16(av1.z); pk.hh[7]=__float2bfloat16(av1.w);
            *(uint4*)(&Lds[nxt][LDSB + ((ach * 64 + (arow ^ ((kwn * 4 + ach) & 31))) << 4)]) = pk.u;
        }
    }

    // ---- epilogue: this wave's 64 rows x 32 j ----
    const int j0 = jt2 * 256 + wave * 32;
    #pragma unroll
    for (int jf = 0; jf < 2; ++jf) {
        const int j = j0 + jf * 16 + t;
        const float bgj = b_gd[j];
        const float bdj = b_gd[HID + j];
        const float btj = b_tau[j];
        const float dcj = dconst[j];
        #pragma unroll
        for (int rf = 0; rf < 4; ++rf) {
            #pragma unroll
            for (int r = 0; r < 4; ++r) {
                const int row = rt * 64 + rf * 16 + q * 4 + r;
                const float gv = acc[rf][jf][0][r] + bgj;
                const float dv = acc[rf][jf][1][r] + bdj;
                const float tp = acc[rf][jf][2][r] + btj;
                const float hv = h_ltc[(size_t)row * HID + j];
                const float sig = __builtin_amdgcn_rcpf(1.0f + __expf(-gv));
                const float th  = 1.0f - 2.0f * __builtin_amdgcn_rcpf(__expf(2.0f * dv) + 1.0f);
                const float tau = fmaxf(tp, 0.0f) + __logf(1.0f + __expf(-fabsf(tp)));
                out[(size_t)row * HID + j] = (sig * th - hv) * __builtin_amdgcn_rcpf(tau + dcj);
            }
        }
    }
}

// ---------------------------------------------------------------------------
extern "C" void kernel_launch(void* const* d_in, const int* in_sizes, int n_in,
                              void* d_out, int out_size, void* d_ws, size_t ws_size,
                              hipStream_t stream) {
    // setup_inputs order: t, h_ltc, x_t, context, W_gd, b_gd, W_tau, b_tau, gleak, cm
    const float* h_ltc = (const float*)d_in[1];
    const float* x_t   = (const float*)d_in[2];
    const float* ctx   = (const float*)d_in[3];
    const float* W_gd  = (const float*)d_in[4];
    const float* b_gd  = (const float*)d_in[5];
    const float* W_tau = (const float*)d_in[6];
    const float* b_tau = (const float*)d_in[7];
    const float* gleak = (const float*)d_in[8];
    const float* cm    = (const float*)d_in[9];

    char* ws = (char*)d_ws;
    __hip_bfloat16* B_stage = (__hip_bfloat16*)ws;      // 8*112*192*8*2 = 2,752,512 B
    float* dconst = (float*)(ws + 2752512);             // 2,048 B

    pack_B<<<672, 256, 0, stream>>>(W_gd, W_tau, gleak, cm, B_stage, dconst);
    ltc_gemm<<<512, 512, 0, stream>>>(x_t, h_ltc, ctx, B_stage, b_gd, b_tau, dconst,
                                      (float*)d_out);
}